// Round 1
// 211.656 us; speedup vs baseline: 1.0154x; 1.0154x over previous
//
#include <hip/hip_runtime.h>

#define NSP 4096
#define HW 512
#define TEMP 0.08838834764831845f  // 128^-0.5
#define MAXE 640                   // max neighbors/node (theoretical bound ~390)
#define PREP_ZERO 512              // blocks zeroing mask (512*256 uint4 = 2 MB)
#define PREP_WF 64                 // blocks computing Wfused (64*256 = 16384 = 128*128)
#define ADJ_BLOCKS 1017            // ceil(510*510/256)
#define QKV_BLOCKS 768             // 4096*48/256

// ---------------- K0: prep = zero adjacency mask || Wfused = Wv @ Wout -----
__global__ void __launch_bounds__(256) prep(
    unsigned int* __restrict__ mask, const float* __restrict__ wqkv,
    const float* __restrict__ wout, float* __restrict__ Wf) {
    int t = threadIdx.x;
    if (blockIdx.x < PREP_ZERO) {
        ((uint4*)mask)[blockIdx.x * 256 + t] = make_uint4(0u, 0u, 0u, 0u);
        return;
    }
    int gid = (blockIdx.x - PREP_ZERO) * 256 + t;    // (d,c) of Wfused
    int d = gid >> 7, c = gid & 127;
    float acc = 0.f;
#pragma unroll 8
    for (int k = 0; k < 128; ++k)
        acc += wqkv[d * 384 + 256 + k] * wout[k * 128 + c];
    Wf[d * 128 + c] = acc;
}

// ---------------- K1: fused adjacency-build + Q/K/V' GEMM (+l2norm) --------
// blocks [0, ADJ_BLOCKS): adjacency bitmask from 2x2 windows
// blocks [ADJ_BLOCKS, +QKV_BLOCKS): q head0, k head0 (l2-normed), V' = x@Wf
__global__ void __launch_bounds__(256) adj_qkv(
    const int* __restrict__ seg, unsigned int* __restrict__ mask,
    const float* __restrict__ spf, const float* __restrict__ wqkv,
    const float* __restrict__ Wf,
    float* __restrict__ Q0, float* __restrict__ K0, float* __restrict__ V) {
    int t = threadIdx.x;
    if (blockIdx.x < ADJ_BLOCKS) {
        int idx = blockIdx.x * 256 + t;
        if (idx >= 510 * 510) return;
        int i = idx / 510, j = idx - i * 510;
        const int* r = seg + i * HW + j;
        int a = r[0], b = r[1], c = r[HW], d = r[HW + 1];
        int mx = max(max(a, b), max(c, d));
        int mn = min(min(a, b), min(c, d));
        if (mx == mn) return;                        // diagonal zeroed in ref
        atomicOr(&mask[mx * 128 + (mn >> 5)], 1u << (mn & 31));
        atomicOr(&mask[mn * 128 + (mx >> 5)], 1u << (mx & 31));
        return;
    }
    int gid = (blockIdx.x - ADJ_BLOCKS) * 256 + t;   // 0 .. 4096*48-1
    int g = gid % 48;
    int n = gid / 48;
    const float* wbase;
    int wstride;
    float* outp;
    if (g < 8)       { wbase = wqkv + g * 4;               wstride = 384; outp = Q0 + n * 32  + g * 4; }
    else if (g < 16) { wbase = wqkv + 128 + (g - 8) * 4;   wstride = 384; outp = K0 + n * 32  + (g - 8) * 4; }
    else             { wbase = Wf + (g - 16) * 4;          wstride = 128; outp = V  + n * 128 + (g - 16) * 4; }
    float4 acc = {0.f, 0.f, 0.f, 0.f};
#pragma unroll 8
    for (int d = 0; d < 128; ++d) {
        float x = spf[d * NSP + n];                  // x[n][d] = spf[d][n]
        float4 w = *(const float4*)(wbase + d * wstride);
        acc.x += x * w.x; acc.y += x * w.y; acc.z += x * w.z; acc.w += x * w.w;
    }
    if (g < 16) {
        // 8 q-threads (8 k-threads) of node n are 8-aligned within one wave:
        // n*48 mod 64 in {0,16,32,48}.
        float s = acc.x * acc.x + acc.y * acc.y + acc.z * acc.z + acc.w * acc.w;
        s += __shfl_xor(s, 1);
        s += __shfl_xor(s, 2);
        s += __shfl_xor(s, 4);
        float inv = 1.0f / fmaxf(sqrtf(s), 1e-12f);
        acc.x *= inv; acc.y *= inv; acc.z *= inv; acc.w *= inv;
    }
    *(float4*)outp = acc;
}

// ---------------- K2: sparse attention -> FINAL node table -----------------
// one block (128 thr) per node n. Diagonal score is exactly 1.0 = row max;
// masked entries underflow to 0. final[n] = (V'[n] + sum w_m V'[m])/(1+sum w_m) + b
__global__ void __launch_bounds__(128) sparse_attn(
    const unsigned int* __restrict__ mask, const float* __restrict__ Q0,
    const float* __restrict__ K0, const float* __restrict__ V,
    const float* __restrict__ bout, float* __restrict__ final) {
    int n = blockIdx.x;
    int t = threadIdx.x;                             // 0..127
    int lane = t & 63, wid = t >> 6;
    __shared__ unsigned int words[128];
    __shared__ int   pfx[128];                       // inclusive scan of popcounts
    __shared__ int   midx[MAXE];
    __shared__ float wts[MAXE];
    __shared__ float q0s[32];
    __shared__ float4 redv[4][32];
    __shared__ float  redw[4];

    unsigned int w = mask[n * 128 + t];
    words[t] = w;
    if (t < 32) q0s[t] = Q0[n * 32 + t];

    // wave-level inclusive scan of popcounts (6 shuffles), then combine waves
    int p = __popc(w);
#pragma unroll
    for (int off = 1; off < 64; off <<= 1) {
        int y = __shfl_up(p, off);
        if (lane >= off) p += y;
    }
    pfx[t] = p;
    __syncthreads();
    if (wid == 1) pfx[t] = p + pfx[63];
    __syncthreads();
    int E = min(pfx[127], MAXE);

    // phase 1: evenly-distributed edge extraction + score
    for (int e = t; e < E; e += 128) {
        int lo = 0, hi = 127;                        // first word with pfx > e
        while (lo < hi) { int mid = (lo + hi) >> 1; if (pfx[mid] > e) hi = mid; else lo = mid + 1; }
        int base = (lo > 0) ? pfx[lo - 1] : 0;
        int r = e - base;
        unsigned int x = words[lo];
        for (int i = 0; i < r; ++i) x &= x - 1;      // r-th set bit
        int m = lo * 32 + (__ffs(x) - 1);
        const float4* kp = (const float4*)(K0 + m * 32);
        float s = 0.f;
#pragma unroll
        for (int i = 0; i < 8; ++i) {
            float4 kv = kp[i];
            s += q0s[i * 4 + 0] * kv.x + q0s[i * 4 + 1] * kv.y +
                 q0s[i * 4 + 2] * kv.z + q0s[i * 4 + 3] * kv.w;
        }
        wts[e]  = __expf(s * TEMP - 1.0f);
        midx[e] = m;
    }
    __syncthreads();

    // phase 2: thread = (edge-group eg, 4-channel group cg); two independent
    // edge streams -> 2 outstanding L2 loads per thread
    int cg = t & 31, eg = t >> 5;
    const float4* V4 = (const float4*)V;
    float4 acc = {0.f, 0.f, 0.f, 0.f};
    float wp = 0.f;
    int e = eg;
    for (; e + 4 < E; e += 8) {
        float wa = wts[e];     int ma = midx[e];
        float wb = wts[e + 4]; int mb = midx[e + 4];
        float4 va = V4[ma * 32 + cg];
        float4 vb = V4[mb * 32 + cg];
        acc.x += wa * va.x + wb * vb.x;
        acc.y += wa * va.y + wb * vb.y;
        acc.z += wa * va.z + wb * vb.z;
        acc.w += wa * va.w + wb * vb.w;
        wp += wa + wb;
    }
    for (; e < E; e += 4) {
        float wt = wts[e];
        float4 v = V4[midx[e] * 32 + cg];
        acc.x += wt * v.x; acc.y += wt * v.y; acc.z += wt * v.z; acc.w += wt * v.w;
        wp += wt;
    }
    redv[eg][cg] = acc;
    if (cg == 0) redw[eg] = wp;
    __syncthreads();
    if (t < 32) {
        float4 a0 = redv[0][t], a1 = redv[1][t], a2 = redv[2][t], a3 = redv[3][t];
        float ws = 1.0f + redw[0] + redw[1] + redw[2] + redw[3];
        float4 vd = V4[n * 32 + t];                  // diagonal, weight e^0 = 1
        float4 bb = ((const float4*)bout)[t];        // bias: softmax rows sum to 1
        float inv = 1.0f / ws;
        float4 o;
        o.x = (a0.x + a1.x + a2.x + a3.x + vd.x) * inv + bb.x;
        o.y = (a0.y + a1.y + a2.y + a3.y + vd.y) * inv + bb.y;
        o.z = (a0.z + a1.z + a2.z + a3.z + vd.z) * inv + bb.z;
        o.w = (a0.w + a1.w + a2.w + a3.w + vd.w) * inv + bb.w;
        ((float4*)final)[n * 32 + t] = o;
    }
}

// ---------------- K3: pixel gather, transposed LDS tile, 1KB/wave stores ---
// Block = 256 pixels x 32 channels. out[c][p] = final[seg[p]][c].
// Phase A: gather final rows (8 lanes x 128B contiguous reads), store LDS
//          TRANSPOSED tile[ch][pix] (pad 260 -> 4-way bank conflict on the
//          scalar writes, hidden under global latency; rows stay 16B-aligned).
// Phase B: each wave reads one channel row as conflict-free ds_read_b128 and
//          stores 64 lanes x float4 = 1 KB FULLY CONTIGUOUS per instruction
//          (vs 16 scattered 64B segments before).
#define GOUT_PIX 256
#define GOUT_CH  32
__global__ void __launch_bounds__(256) gather_out(
    const float* __restrict__ final, const int* __restrict__ seg,
    float* __restrict__ out) {
    __shared__ __align__(16) float tile[GOUT_CH][260];  // 1040B rows: 16B-aligned
    __shared__ int sseg[GOUT_PIX];
    int t = threadIdx.x;
    int pixbase = (blockIdx.x >> 2) * GOUT_PIX;
    int cbase = (blockIdx.x & 3) * GOUT_CH;             // channel-group base

    sseg[t] = seg[pixbase + t];
    __syncthreads();

    const float4* f4 = (const float4*)final;
    int c8 = t & 7;                                     // float4-col in 32-ch strip
    int pp = t >> 3;                                    // 0..31
#pragma unroll
    for (int i = 0; i < 8; ++i) {
        int p = pp + 32 * i;
        float4 v = f4[sseg[p] * 32 + (cbase >> 2) + c8];
        tile[4 * c8 + 0][p] = v.x;
        tile[4 * c8 + 1][p] = v.y;
        tile[4 * c8 + 2][p] = v.z;
        tile[4 * c8 + 3][p] = v.w;
    }
    __syncthreads();

    int wv = t >> 6, lane = t & 63;
#pragma unroll
    for (int s = 0; s < 8; ++s) {
        int ch = wv * 8 + s;
        float4 v = *(const float4*)&tile[ch][4 * lane];
        *(float4*)(out + (size_t)(cbase + ch) * (HW * HW) + pixbase + 4 * lane) = v;
    }
}

extern "C" void kernel_launch(void* const* d_in, const int* in_sizes, int n_in,
                              void* d_out, int out_size, void* d_ws, size_t ws_size,
                              hipStream_t stream) {
    const float* spf  = (const float*)d_in[0];   // (128, 4096)
    const int*   seg  = (const int*)d_in[1];     // (512, 512)
    const float* wqkv = (const float*)d_in[2];   // (128, 384)
    const float* wout = (const float*)d_in[3];   // (128, 128)
    const float* bout = (const float*)d_in[4];   // (128,)
    float* out = (float*)d_out;                  // (1,128,512,512)

    char* ws = (char*)d_ws;                      // needs ~7.1 MB
    unsigned int* mask = (unsigned int*)ws;                     // 2 MB
    float* Q0    = (float*)(ws + (2u << 20));                   // 512 KB
    float* K0    = (float*)(ws + (2u << 20) + (512u << 10));    // 512 KB
    float* V     = (float*)(ws + (3u << 20));                   // 2 MB (= x @ Wfused)
    float* final = (float*)(ws + (5u << 20));                   // 2 MB
    float* Wf    = (float*)(ws + (7u << 20));                   // 64 KB

    hipLaunchKernelGGL(prep, dim3(PREP_ZERO + PREP_WF), dim3(256), 0, stream,
                       mask, wqkv, wout, Wf);
    hipLaunchKernelGGL(adj_qkv, dim3(ADJ_BLOCKS + QKV_BLOCKS), dim3(256), 0, stream,
                       seg, mask, spf, wqkv, Wf, Q0, K0, V);
    hipLaunchKernelGGL(sparse_attn, dim3(4096), dim3(128), 0, stream,
                       mask, Q0, K0, V, bout, final);
    hipLaunchKernelGGL(gather_out, dim3((HW * HW / GOUT_PIX) * 4), dim3(256), 0, stream,
                       final, seg, out);
}